// Round 3
// baseline (232.053 us; speedup 1.0000x reference)
//
#include <hip/hip_runtime.h>

#define CLASS_NUM 19
#define NBINS (CLASS_NUM * CLASS_NUM)   // 361
#define HW (512 * 512)                  // 262144
#define NPIX (8 * HW)                   // 2097152
#define NVEC (NPIX / 4)                 // 524288 pixel-quads
#define HWV (HW / 4)                    // 65536 float4 per channel-image

__global__ void zero_out_kernel(int* __restrict__ out) {
    int t = threadIdx.x;
    if (t < NBINS) out[t] = 0;
}

__device__ __forceinline__ float max3(float a, float b, float c) {
    return fmaxf(fmaxf(a, b), c);      // fuses to v_max3_f32
}

// One pixel-quad per thread: 1024 blocks x 512 threads = 524288 threads.
// Argmax = max3-tree (3-deep, 9 instr/comp) + descending equality scan
// (2 instr/elem, first-occurrence tie semantics preserved).
__global__ __launch_bounds__(512, 4) void confusion_kernel(
    const float4* __restrict__ in,   // [B, C, HWV] as float4
    const int4*  __restrict__ tgt,   // [B, HWV] as int4
    int* __restrict__ out)           // [361]
{
    __shared__ int hist[NBINS];
    for (int i = threadIdx.x; i < NBINS; i += 512) hist[i] = 0;
    __syncthreads();

    const int g   = blockIdx.x * 512 + threadIdx.x;   // [0, NVEC)
    const int b   = g >> 16;                          // g / HWV
    const int hwv = g & (HWV - 1);                    // g % HWV
    const float4* p = in + (size_t)b * (CLASS_NUM * HWV) + hwv;

    const int4 t = tgt[g];            // issue target load first

    // Component-major register arrays: a[comp][channel]
    float a0[CLASS_NUM], a1[CLASS_NUM], a2[CLASS_NUM], a3[CLASS_NUM];
    #pragma unroll
    for (int c = 0; c < CLASS_NUM; ++c) {
        float4 v = p[(size_t)c * HWV];
        a0[c] = v.x; a1[c] = v.y; a2[c] = v.z; a3[c] = v.w;
    }

    #define ARGMAX(a, idx)                                                   \
        int idx;                                                             \
        {                                                                    \
            float m0 = max3(a[0],  a[1],  a[2]);                             \
            float m1 = max3(a[3],  a[4],  a[5]);                             \
            float m2 = max3(a[6],  a[7],  a[8]);                             \
            float m3 = max3(a[9],  a[10], a[11]);                            \
            float m4 = max3(a[12], a[13], a[14]);                            \
            float m5 = max3(a[15], a[16], a[17]);                            \
            float n0 = max3(m0, m1, m2);                                     \
            float n1 = max3(m3, m4, m5);                                     \
            float m  = max3(n0, n1, a[18]);                                  \
            idx = 18;                                                        \
            _Pragma("unroll")                                                \
            for (int c = 17; c >= 0; --c) idx = (a[c] == m) ? c : idx;       \
        }

    ARGMAX(a0, i0)
    ARGMAX(a1, i1)
    ARGMAX(a2, i2)
    ARGMAX(a3, i3)

    atomicAdd(&hist[t.x * CLASS_NUM + i0], 1);
    atomicAdd(&hist[t.y * CLASS_NUM + i1], 1);
    atomicAdd(&hist[t.z * CLASS_NUM + i2], 1);
    atomicAdd(&hist[t.w * CLASS_NUM + i3], 1);

    __syncthreads();
    for (int i = threadIdx.x; i < NBINS; i += 512) {
        int h = hist[i];
        if (h) atomicAdd(&out[i], h);
    }
}

extern "C" void kernel_launch(void* const* d_in, const int* in_sizes, int n_in,
                              void* d_out, int out_size, void* d_ws, size_t ws_size,
                              hipStream_t stream) {
    const float4* in  = (const float4*)d_in[0];
    const int4*   tgt = (const int4*)d_in[1];
    int* out = (int*)d_out;

    // d_out is re-poisoned to 0xAA before every timed launch — zero it first.
    zero_out_kernel<<<1, 512, 0, stream>>>(out);

    confusion_kernel<<<NVEC / 512, 512, 0, stream>>>(in, tgt, out);
}